// Round 1
// baseline (4615.159 us; speedup 1.0000x reference)
//
#include <hip/hip_runtime.h>
#include <math.h>

// Problem constants (fixed-shape problem)
#define NNODES  200000
#define NEDGES  6400000
#define NGRAPHS 512
#define FIN     92
#define WID     10

// ---------------------------------------------------------------------------
// K1: per-edge weight ew = exp(-||r||^2) and unweighted degree histograms
// ---------------------------------------------------------------------------
__global__ void k_edge_prep(const float* __restrict__ r,
                            const int* __restrict__ src,
                            const int* __restrict__ dst,
                            float* __restrict__ ew,
                            float* __restrict__ outdeg,
                            float* __restrict__ indeg) {
    int e = blockIdx.x * blockDim.x + threadIdx.x;
    if (e >= NEDGES) return;
    float x = r[3 * e + 0];
    float y = r[3 * e + 1];
    float z = r[3 * e + 2];
    ew[e] = expf(-(x * x + y * y + z * z));
    atomicAdd(&outdeg[src[e]], 1.0f);
    atomicAdd(&indeg[dst[e]], 1.0f);
}

// ---------------------------------------------------------------------------
// K2: deg -> 1/sqrt(max(deg,1)), in place
// ---------------------------------------------------------------------------
__global__ void k_invsqrt(float* __restrict__ outdeg, float* __restrict__ indeg) {
    int n = blockIdx.x * blockDim.x + threadIdx.x;
    if (n >= NNODES) return;
    float od = outdeg[n];
    od = od < 1.0f ? 1.0f : od;
    outdeg[n] = 1.0f / sqrtf(od);
    float id = indeg[n];
    id = id < 1.0f ? 1.0f : id;
    indeg[n] = 1.0f / sqrtf(id);
}

// ---------------------------------------------------------------------------
// K3: hs[n,:] = (A[n,:] @ W_emb + b_emb) * inv_sqrt_out[n]
// (embedding fused with the gconv1 source-side degree scaling)
// ---------------------------------------------------------------------------
__global__ void k_embed(const float* __restrict__ A,
                        const float* __restrict__ Wemb,
                        const float* __restrict__ bemb,
                        const float* __restrict__ inv_out,
                        float* __restrict__ hs) {
    __shared__ float sW[FIN * WID];
    __shared__ float sb[WID];
    for (int i = threadIdx.x; i < FIN * WID; i += blockDim.x) sW[i] = Wemb[i];
    if (threadIdx.x < WID) sb[threadIdx.x] = bemb[threadIdx.x];
    __syncthreads();

    int n = blockIdx.x * blockDim.x + threadIdx.x;
    if (n >= NNODES) return;

    float acc[WID];
#pragma unroll
    for (int k = 0; k < WID; k++) acc[k] = sb[k];

    // row is 92 floats = 368 B; 368 % 16 == 0 -> aligned float4 loads
    const float4* row4 = reinterpret_cast<const float4*>(A + (size_t)n * FIN);
#pragma unroll
    for (int f4 = 0; f4 < FIN / 4; f4++) {
        float4 v = row4[f4];
        int f = f4 * 4;
#pragma unroll
        for (int k = 0; k < WID; k++) acc[k] += v.x * sW[(f + 0) * WID + k];
#pragma unroll
        for (int k = 0; k < WID; k++) acc[k] += v.y * sW[(f + 1) * WID + k];
#pragma unroll
        for (int k = 0; k < WID; k++) acc[k] += v.z * sW[(f + 2) * WID + k];
#pragma unroll
        for (int k = 0; k < WID; k++) acc[k] += v.w * sW[(f + 3) * WID + k];
    }

    float sc = inv_out[n];
    float* out = hs + (size_t)n * WID;
#pragma unroll
    for (int k = 0; k < WID; k++) out[k] = acc[k] * sc;
}

// ---------------------------------------------------------------------------
// K4: gconv1 message scatter: agg1[dst,:] += ew * hs[src,:]
// ---------------------------------------------------------------------------
__global__ void k_scatter1(const int* __restrict__ src,
                           const int* __restrict__ dst,
                           const float* __restrict__ ew,
                           const float* __restrict__ hs,
                           float* __restrict__ agg1) {
    int e = blockIdx.x * blockDim.x + threadIdx.x;
    if (e >= NEDGES) return;
    int s = src[e];
    int d = dst[e];
    float w = ew[e];
    const float* hrow = hs + (size_t)s * WID;
    float* arow = agg1 + (size_t)d * WID;
#pragma unroll
    for (int k = 0; k < WID; k++) atomicAdd(&arow[k], w * hrow[k]);
}

// ---------------------------------------------------------------------------
// K5: node update for gconv1 + projection for gconv2
//   y = agg1[n,:] @ W1 ; x1 = relu(y * inv_in[n] + b1)
//   sproj[n] = inv_out[n] * (x1 . W2)
// ---------------------------------------------------------------------------
__global__ void k_update(const float* __restrict__ agg1,
                         const float* __restrict__ W1,
                         const float* __restrict__ b1,
                         const float* __restrict__ W2,
                         const float* __restrict__ inv_in,
                         const float* __restrict__ inv_out,
                         float* __restrict__ sproj) {
    __shared__ float sW1[WID * WID];
    __shared__ float sb1[WID];
    __shared__ float sW2[WID];
    for (int i = threadIdx.x; i < WID * WID; i += blockDim.x) sW1[i] = W1[i];
    if (threadIdx.x < WID) {
        sb1[threadIdx.x] = b1[threadIdx.x];
        sW2[threadIdx.x] = W2[threadIdx.x];
    }
    __syncthreads();

    int n = blockIdx.x * blockDim.x + threadIdx.x;
    if (n >= NNODES) return;

    float a[WID];
    const float* arow = agg1 + (size_t)n * WID;
#pragma unroll
    for (int k = 0; k < WID; k++) a[k] = arow[k];

    float ii = inv_in[n];
    float dot = 0.0f;
#pragma unroll
    for (int j = 0; j < WID; j++) {
        float y = 0.0f;
#pragma unroll
        for (int k = 0; k < WID; k++) y += a[k] * sW1[k * WID + j];
        y = y * ii + sb1[j];
        y = y > 0.0f ? y : 0.0f;  // relu
        dot += y * sW2[j];
    }
    sproj[n] = dot * inv_out[n];
}

// ---------------------------------------------------------------------------
// K6: gconv2 scalar scatter: agg2[dst] += ew * sproj[src]
// ---------------------------------------------------------------------------
__global__ void k_scatter2(const int* __restrict__ src,
                           const int* __restrict__ dst,
                           const float* __restrict__ ew,
                           const float* __restrict__ sproj,
                           float* __restrict__ agg2) {
    int e = blockIdx.x * blockDim.x + threadIdx.x;
    if (e >= NEDGES) return;
    atomicAdd(&agg2[dst[e]], ew[e] * sproj[src[e]]);
}

// ---------------------------------------------------------------------------
// K7: per-node output + graph pooling accumulation
// ---------------------------------------------------------------------------
__global__ void k_pool(const float* __restrict__ agg2,
                       const float* __restrict__ inv_in,
                       const float* __restrict__ b2,
                       const int* __restrict__ graph_ids,
                       float* __restrict__ pooled,
                       float* __restrict__ cnt) {
    int n = blockIdx.x * blockDim.x + threadIdx.x;
    if (n >= NNODES) return;
    float v = agg2[n] * inv_in[n] + b2[0];
    int g = graph_ids[n];
    atomicAdd(&pooled[g], v);
    atomicAdd(&cnt[g], 1.0f);
}

// ---------------------------------------------------------------------------
// K8: finalize: out[g] = pooled[g] / cnt[g]
// ---------------------------------------------------------------------------
__global__ void k_final(const float* __restrict__ pooled,
                        const float* __restrict__ cnt,
                        float* __restrict__ out) {
    int g = blockIdx.x * blockDim.x + threadIdx.x;
    if (g >= NGRAPHS) return;
    out[g] = pooled[g] / cnt[g];
}

// ---------------------------------------------------------------------------
extern "C" void kernel_launch(void* const* d_in, const int* in_sizes, int n_in,
                              void* d_out, int out_size, void* d_ws, size_t ws_size,
                              hipStream_t stream) {
    const float* atom = (const float*)d_in[0];
    const float* r    = (const float*)d_in[1];
    const float* Wemb = (const float*)d_in[2];
    const float* bemb = (const float*)d_in[3];
    const float* W1   = (const float*)d_in[4];
    const float* b1   = (const float*)d_in[5];
    const float* W2   = (const float*)d_in[6];
    const float* b2   = (const float*)d_in[7];
    const int*   src  = (const int*)d_in[8];
    const int*   dst  = (const int*)d_in[9];
    const int*   gids = (const int*)d_in[10];

    float* out = (float*)d_out;

    // Workspace layout (floats). Zero region first (accumulators), then scratch.
    float* w = (float*)d_ws;
    float* agg1   = w; w += (size_t)NNODES * WID;   // 2,000,000
    float* agg2   = w; w += NNODES;                 //   200,000
    float* outdeg = w; w += NNODES;                 //   200,000 (becomes inv_sqrt_out)
    float* indeg  = w; w += NNODES;                 //   200,000 (becomes inv_sqrt_in)
    float* pooled = w; w += NGRAPHS;                //       512
    float* cnt    = w; w += NGRAPHS;                //       512
    size_t zero_floats = (size_t)(w - (float*)d_ws);
    float* ew    = w; w += NEDGES;                  // 6,400,000
    float* hs    = w; w += (size_t)NNODES * WID;    // 2,000,000
    float* sproj = w; w += NNODES;                  //   200,000
    // total ~ 11.2M floats ~ 44.8 MB

    hipMemsetAsync(d_ws, 0, zero_floats * sizeof(float), stream);

    const int B = 256;
    const int gridE = (NEDGES + B - 1) / B;
    const int gridN = (NNODES + B - 1) / B;
    const int gridG = (NGRAPHS + B - 1) / B;

    k_edge_prep<<<gridE, B, 0, stream>>>(r, src, dst, ew, outdeg, indeg);
    k_invsqrt<<<gridN, B, 0, stream>>>(outdeg, indeg);
    k_embed<<<gridN, B, 0, stream>>>(atom, Wemb, bemb, outdeg, hs);
    k_scatter1<<<gridE, B, 0, stream>>>(src, dst, ew, hs, agg1);
    k_update<<<gridN, B, 0, stream>>>(agg1, W1, b1, W2, indeg, outdeg, sproj);
    k_scatter2<<<gridE, B, 0, stream>>>(src, dst, ew, sproj, agg2);
    k_pool<<<gridN, B, 0, stream>>>(agg2, indeg, b2, gids, pooled, cnt);
    k_final<<<gridG, B, 0, stream>>>(pooled, cnt, out);
}

// Round 3
// 1332.784 us; speedup vs baseline: 3.4628x; 3.4628x over previous
//
#include <hip/hip_runtime.h>
#include <math.h>

#define NNODES  200000
#define NEDGES  6400000
#define NGRAPHS 512
#define FIN     92
#define WID     10
#define HPAD    16                     // hs row padded to 16 floats (64 B)
#define NBLK    ((NNODES + 255) / 256) // 782

// ---------------------------------------------------------------------------
// K1: unweighted degree histograms (int). 2 atomics/edge -- the atomic floor.
// ---------------------------------------------------------------------------
__global__ void k_edge_prep(const int* __restrict__ src,
                            const int* __restrict__ dst,
                            int* __restrict__ outdeg_cnt,
                            int* __restrict__ indeg_cnt) {
    int e = blockIdx.x * blockDim.x + threadIdx.x;
    if (e >= NEDGES) return;
    atomicAdd(&outdeg_cnt[src[e]], 1);
    atomicAdd(&indeg_cnt[dst[e]], 1);
}

// ---------------------------------------------------------------------------
// K2: per-block partial sums of indeg counts (scan step 1)
// ---------------------------------------------------------------------------
__global__ void k_scan_partial(const int* __restrict__ cnt,
                               int* __restrict__ partial) {
    __shared__ int sdata[256];
    int tid = threadIdx.x;
    int i = blockIdx.x * 256 + tid;
    int v = (i < NNODES) ? cnt[i] : 0;
    sdata[tid] = v;
    __syncthreads();
    for (int s = 128; s > 0; s >>= 1) {
        if (tid < s) sdata[tid] += sdata[tid + s];
        __syncthreads();
    }
    if (tid == 0) partial[blockIdx.x] = sdata[0];
}

// ---------------------------------------------------------------------------
// K3: single-block exclusive scan of the 782 partials (scan step 2)
// ---------------------------------------------------------------------------
__global__ void k_scan_top(int* __restrict__ partial) {
    __shared__ int buf[1024];
    int tid = threadIdx.x;
    int v = (tid < NBLK) ? partial[tid] : 0;
    buf[tid] = v;
    __syncthreads();
    for (int off = 1; off < 1024; off <<= 1) {
        int t = (tid >= off) ? buf[tid - off] : 0;
        __syncthreads();
        buf[tid] += t;
        __syncthreads();
    }
    if (tid < NBLK) partial[tid] = buf[tid] - v;  // exclusive
}

// ---------------------------------------------------------------------------
// K4: row_ptr (exclusive scan within block + block offset), inv-sqrt degrees,
//     and re-zero indeg_cnt so it can be reused as the CSR fill cursor.
// ---------------------------------------------------------------------------
__global__ void k_rowptr(int* __restrict__ indeg_cnt,
                         const int* __restrict__ outdeg_cnt,
                         const int* __restrict__ partial,
                         int* __restrict__ row_ptr,
                         float* __restrict__ inv_in,
                         float* __restrict__ inv_out) {
    __shared__ int buf[256];
    int tid = threadIdx.x;
    int n = blockIdx.x * 256 + tid;
    int c = (n < NNODES) ? indeg_cnt[n] : 0;
    buf[tid] = c;
    __syncthreads();
    for (int off = 1; off < 256; off <<= 1) {
        int t = (tid >= off) ? buf[tid - off] : 0;
        __syncthreads();
        buf[tid] += t;
        __syncthreads();
    }
    int excl = buf[tid] - c + partial[blockIdx.x];
    if (n < NNODES) {
        row_ptr[n] = excl;
        inv_in[n] = rsqrtf((float)(c < 1 ? 1 : c));
        int oc = outdeg_cnt[n];
        inv_out[n] = rsqrtf((float)(oc < 1 ? 1 : oc));
        indeg_cnt[n] = 0;  // reuse as fill cursor
        if (n == NNODES - 1) row_ptr[NNODES] = excl + c;  // sentinel
    }
}

// ---------------------------------------------------------------------------
// K5: hs[n,:] = (A[n,:] @ W_emb + b_emb) * inv_sqrt_out[n], padded rows
// ---------------------------------------------------------------------------
__global__ void k_embed(const float* __restrict__ A,
                        const float* __restrict__ Wemb,
                        const float* __restrict__ bemb,
                        const float* __restrict__ inv_out,
                        float* __restrict__ hs) {
    __shared__ float sW[FIN * WID];
    __shared__ float sb[WID];
    for (int i = threadIdx.x; i < FIN * WID; i += blockDim.x) sW[i] = Wemb[i];
    if (threadIdx.x < WID) sb[threadIdx.x] = bemb[threadIdx.x];
    __syncthreads();

    int n = blockIdx.x * blockDim.x + threadIdx.x;
    if (n >= NNODES) return;

    float acc[WID];
#pragma unroll
    for (int k = 0; k < WID; k++) acc[k] = sb[k];

    const float4* row4 = reinterpret_cast<const float4*>(A + (size_t)n * FIN);
#pragma unroll
    for (int f4 = 0; f4 < FIN / 4; f4++) {
        float4 v = row4[f4];
        int f = f4 * 4;
#pragma unroll
        for (int k = 0; k < WID; k++) acc[k] += v.x * sW[(f + 0) * WID + k];
#pragma unroll
        for (int k = 0; k < WID; k++) acc[k] += v.y * sW[(f + 1) * WID + k];
#pragma unroll
        for (int k = 0; k < WID; k++) acc[k] += v.z * sW[(f + 2) * WID + k];
#pragma unroll
        for (int k = 0; k < WID; k++) acc[k] += v.w * sW[(f + 3) * WID + k];
    }

    float sc = inv_out[n];
    float* out = hs + (size_t)n * HPAD;
    float4 o0 = make_float4(acc[0] * sc, acc[1] * sc, acc[2] * sc, acc[3] * sc);
    float4 o1 = make_float4(acc[4] * sc, acc[5] * sc, acc[6] * sc, acc[7] * sc);
    float2 o2 = make_float2(acc[8] * sc, acc[9] * sc);
    *reinterpret_cast<float4*>(out + 0) = o0;
    *reinterpret_cast<float4*>(out + 4) = o1;
    *reinterpret_cast<float2*>(out + 8) = o2;
}

// ---------------------------------------------------------------------------
// K6: counting-sort fill: csr[pos] = (w = exp(-||r||^2), src bits)
// ---------------------------------------------------------------------------
__global__ void k_csr_fill(const float* __restrict__ r,
                           const int* __restrict__ src,
                           const int* __restrict__ dst,
                           const int* __restrict__ row_ptr,
                           int* __restrict__ fillcnt,
                           float2* __restrict__ csr) {
    int e = blockIdx.x * blockDim.x + threadIdx.x;
    if (e >= NEDGES) return;
    float x = r[3 * e + 0];
    float y = r[3 * e + 1];
    float z = r[3 * e + 2];
    float w = expf(-(x * x + y * y + z * z));
    int s = src[e];
    int d = dst[e];
    int pos = row_ptr[d] + atomicAdd(&fillcnt[d], 1);
    csr[pos] = make_float2(w, __int_as_float(s));
}

// ---------------------------------------------------------------------------
// K7: pull-mode aggregate of gconv1 FUSED with node update + gconv2 proj:
//   acc = sum_e w_e * hs[src_e];  y = relu((acc @ W1)*inv_in + b1)
//   sproj[n] = (y . W2) * inv_out[n]
// ---------------------------------------------------------------------------
__global__ void k_agg1(const float2* __restrict__ csr,
                       const int* __restrict__ row_ptr,
                       const float* __restrict__ hs,
                       const float* __restrict__ W1,
                       const float* __restrict__ b1,
                       const float* __restrict__ W2,
                       const float* __restrict__ inv_in,
                       const float* __restrict__ inv_out,
                       float* __restrict__ sproj) {
    __shared__ float sW1[WID * WID];
    __shared__ float sb1[WID];
    __shared__ float sW2[WID];
    for (int i = threadIdx.x; i < WID * WID; i += blockDim.x) sW1[i] = W1[i];
    if (threadIdx.x < WID) {
        sb1[threadIdx.x] = b1[threadIdx.x];
        sW2[threadIdx.x] = W2[threadIdx.x];
    }
    __syncthreads();

    int n = blockIdx.x * blockDim.x + threadIdx.x;
    if (n >= NNODES) return;

    int start = row_ptr[n];
    int end = row_ptr[n + 1];

    float acc[WID];
#pragma unroll
    for (int k = 0; k < WID; k++) acc[k] = 0.0f;

    for (int p = start; p < end; p++) {
        float2 c2 = csr[p];
        float w = c2.x;
        int s = __float_as_int(c2.y);
        const float* hrow = hs + (size_t)s * HPAD;
        float4 a = *reinterpret_cast<const float4*>(hrow + 0);
        float4 b = *reinterpret_cast<const float4*>(hrow + 4);
        float2 c = *reinterpret_cast<const float2*>(hrow + 8);
        acc[0] += w * a.x; acc[1] += w * a.y; acc[2] += w * a.z; acc[3] += w * a.w;
        acc[4] += w * b.x; acc[5] += w * b.y; acc[6] += w * b.z; acc[7] += w * b.w;
        acc[8] += w * c.x; acc[9] += w * c.y;
    }

    float ii = inv_in[n];
    float dot = 0.0f;
#pragma unroll
    for (int j = 0; j < WID; j++) {
        float y = 0.0f;
#pragma unroll
        for (int k = 0; k < WID; k++) y += acc[k] * sW1[k * WID + j];
        y = y * ii + sb1[j];
        y = y > 0.0f ? y : 0.0f;
        dot += y * sW2[j];
    }
    sproj[n] = dot * inv_out[n];
}

// ---------------------------------------------------------------------------
// K8: pull-mode scalar aggregate of gconv2 FUSED with graph pooling.
//   v_n = (sum_e w_e * sproj[src_e]) * inv_in[n] + b2
//   pooled[g] += v_n  via wave-segmented reduction (graph_ids sorted)
// NOTE: __shfl_down clamps out-of-range source lanes to SELF on AMD, which
// makes the segment check trivially true -> self-doubling. Guard with
// lane + off < 64 (this was the round-2 correctness bug, absmax 2.5e-3).
// ---------------------------------------------------------------------------
__global__ void k_agg2_pool(const float2* __restrict__ csr,
                            const int* __restrict__ row_ptr,
                            const float* __restrict__ sproj,
                            const float* __restrict__ inv_in,
                            const float* __restrict__ b2,
                            const int* __restrict__ graph_ids,
                            float* __restrict__ pooled) {
    int n = blockIdx.x * blockDim.x + threadIdx.x;
    int lane = threadIdx.x & 63;

    float v = 0.0f;
    int g = -1;
    if (n < NNODES) {
        int start = row_ptr[n];
        int end = row_ptr[n + 1];
        float sum = 0.0f;
        for (int p = start; p < end; p++) {
            float2 c2 = csr[p];
            sum += c2.x * sproj[__float_as_int(c2.y)];
        }
        v = sum * inv_in[n] + b2[0];
        g = graph_ids[n];
    }

    // segmented suffix-sum within the wave (gids sorted => endpoint check ok)
#pragma unroll
    for (int off = 1; off < 64; off <<= 1) {
        float vv = __shfl_down(v, off, 64);
        int gg = __shfl_down(g, off, 64);
        if (lane + off < 64 && gg == g) v += vv;
    }
    int gprev = __shfl_up(g, 1, 64);
    bool head = (lane == 0) || (gprev != g);
    if (g >= 0 && head) atomicAdd(&pooled[g], v);
}

// ---------------------------------------------------------------------------
// K9: out[g] = pooled[g] / count(g); counts via binary search on sorted gids
// ---------------------------------------------------------------------------
__global__ void k_final(const float* __restrict__ pooled,
                        const int* __restrict__ gids,
                        float* __restrict__ out) {
    int g = blockIdx.x * blockDim.x + threadIdx.x;
    if (g >= NGRAPHS) return;
    int lo = 0, hi = NNODES;
    while (lo < hi) { int m = (lo + hi) >> 1; if (gids[m] < g) lo = m + 1; else hi = m; }
    int first = lo;
    hi = NNODES;
    while (lo < hi) { int m = (lo + hi) >> 1; if (gids[m] < g + 1) lo = m + 1; else hi = m; }
    int cnt = lo - first;
    out[g] = pooled[g] / (float)(cnt > 0 ? cnt : 1);
}

// ---------------------------------------------------------------------------
extern "C" void kernel_launch(void* const* d_in, const int* in_sizes, int n_in,
                              void* d_out, int out_size, void* d_ws, size_t ws_size,
                              hipStream_t stream) {
    const float* atom = (const float*)d_in[0];
    const float* r    = (const float*)d_in[1];
    const float* Wemb = (const float*)d_in[2];
    const float* bemb = (const float*)d_in[3];
    const float* W1   = (const float*)d_in[4];
    const float* b1   = (const float*)d_in[5];
    const float* W2   = (const float*)d_in[6];
    const float* b2   = (const float*)d_in[7];
    const int*   src  = (const int*)d_in[8];
    const int*   dst  = (const int*)d_in[9];
    const int*   gids = (const int*)d_in[10];
    float* out = (float*)d_out;

    // Workspace layout (all chunks 16B-aligned).
    char* w = (char*)d_ws;
    // -- zeroed region --
    int*   indeg_cnt  = (int*)w;    w += (size_t)NNODES * 4;     // also fill cursor
    int*   outdeg_cnt = (int*)w;    w += (size_t)NNODES * 4;
    float* pooled     = (float*)w;  w += (size_t)NGRAPHS * 4;
    size_t zero_bytes = (size_t)(w - (char*)d_ws);
    // -- scratch --
    int*    row_ptr = (int*)w;      w += (size_t)(NNODES + 4) * 4;
    float*  inv_in  = (float*)w;    w += (size_t)NNODES * 4;
    float*  inv_out = (float*)w;    w += (size_t)NNODES * 4;
    float*  hs      = (float*)w;    w += (size_t)NNODES * HPAD * 4;
    float*  sproj   = (float*)w;    w += (size_t)NNODES * 4;
    int*    partial = (int*)w;      w += (size_t)((NBLK + 3) & ~3) * 4;
    float2* csr     = (float2*)w;   w += (size_t)NEDGES * 8;
    // total ~ 68.8 MB

    hipMemsetAsync(d_ws, 0, zero_bytes, stream);

    const int B = 256;
    const int gridE = (NEDGES + B - 1) / B;
    const int gridN = NBLK;

    k_edge_prep<<<gridE, B, 0, stream>>>(src, dst, outdeg_cnt, indeg_cnt);
    k_scan_partial<<<gridN, B, 0, stream>>>(indeg_cnt, partial);
    k_scan_top<<<1, 1024, 0, stream>>>(partial);
    k_rowptr<<<gridN, B, 0, stream>>>(indeg_cnt, outdeg_cnt, partial,
                                      row_ptr, inv_in, inv_out);
    k_embed<<<gridN, B, 0, stream>>>(atom, Wemb, bemb, inv_out, hs);
    k_csr_fill<<<gridE, B, 0, stream>>>(r, src, dst, row_ptr, indeg_cnt, csr);
    k_agg1<<<gridN, B, 0, stream>>>(csr, row_ptr, hs, W1, b1, W2,
                                    inv_in, inv_out, sproj);
    k_agg2_pool<<<gridN, B, 0, stream>>>(csr, row_ptr, sproj, inv_in, b2,
                                         gids, pooled);
    k_final<<<(NGRAPHS + B - 1) / B, B, 0, stream>>>(pooled, gids, out);
}